// Round 4
// baseline (259.658 us; speedup 1.0000x reference)
//
#include <hip/hip_runtime.h>
#include <hip/hip_bf16.h>

typedef __bf16 bf16x8_t __attribute__((ext_vector_type(8)));
typedef float  f32x4_t  __attribute__((ext_vector_type(4)));
typedef short  short8_t __attribute__((ext_vector_type(8)));
typedef short  short4_t __attribute__((ext_vector_type(4)));

#define NB   4
#define NH   16
#define SEQ  2048
#define HD   64
#define QT   64    // q rows per fragment set; block owns two complementary q-tiles
#define BKV  64
#define NQT  (SEQ / QT)   // 32 q-tiles total
#define LSTR 72    // LDS row stride in bf16 elems: 144B rows, 16B-aligned blocks

// masked score in base-2 domain: WHERE_CONST * log2(e)
#define MASK2 (-14426.950408889634f)
// softmax scale folded into Q: (1/sqrt(64)) * log2(e)
#define QSCL  (0.18033688011112042f)

// uniform swizzled LDS address (shorts): row*72 + ((blk ^ (row>>3)) & 7) * 8
__device__ __forceinline__ int swz(int rowi, int blk) {
    return rowi * LSTR + (((blk) ^ (rowi >> 3)) & 7) * 8;
}

__global__ void __launch_bounds__(256)
fa_fwd(const float* __restrict__ qg,
       const float* __restrict__ kg,
       const float* __restrict__ vg,
       float* __restrict__ outg) {
    __shared__ alignas(16) short k_lds[BKV * LSTR];    // K tile bf16 [kv][d], block-swizzled
    __shared__ alignas(16) short vt_lds[HD * LSTR];    // V^T tile bf16 [d][kv], block-swizzled
    __shared__ alignas(16) short p_lds[2 * QT * LSTR]; // P bf16: A rows 0-63, B rows 64-127

    const int tid  = threadIdx.x;
    const int wave = tid >> 6;
    const int lane = tid & 63;
    const int l16  = lane & 15;
    const int quad = lane >> 4;

    // grid: x = bh (64), y = pair index i (16). Pair = q-tiles (i, 31-i):
    // compute per block = (i+1) + (32-i) = 33 tile-units for EVERY block.
    const int bh = blockIdx.x;
    const int pi = blockIdx.y;          // i=0 (heaviest staging) dispatches first
    const int qtA = pi;
    const int qtB = (NQT - 1) - pi;
    const int q0A = qtA * QT;
    const int q0B = qtB * QT;
    const int ntA = qtA + 1;            // KV tiles set A needs
    const int ntB = qtB + 1;            // KV tiles set B needs (> ntA always)

    const size_t base = (size_t)bh * SEQ * HD;
    const float* qp = qg + base;
    const float* kp = kg + base;
    const float* vp = vg + base;

    // ---- Q fragments (B-operand in swapped QK^T): q=l16-row, d=quad*8+j ----
    bf16x8_t qfA0, qfA1, qfB0, qfB1;
    auto load_q = [&](int row, bf16x8_t& f0, bf16x8_t& f1) {
        const float* qr = qp + (size_t)row * HD;
        f32x4_t a0 = *(const f32x4_t*)(qr + quad * 8);
        f32x4_t a1 = *(const f32x4_t*)(qr + quad * 8 + 4);
        f32x4_t a2 = *(const f32x4_t*)(qr + 32 + quad * 8);
        f32x4_t a3 = *(const f32x4_t*)(qr + 32 + quad * 8 + 4);
        #pragma unroll
        for (int j = 0; j < 4; ++j) {
            f0[j]     = (__bf16)(a0[j] * QSCL);
            f0[4 + j] = (__bf16)(a1[j] * QSCL);
            f1[j]     = (__bf16)(a2[j] * QSCL);
            f1[4 + j] = (__bf16)(a3[j] * QSCL);
        }
    };
    load_q(q0A + wave * 16 + l16, qfA0, qfA1);
    load_q(q0B + wave * 16 + l16, qfB0, qfB1);

    f32x4_t oA[4], oB[4];
    const f32x4_t zero4 = {0.0f, 0.0f, 0.0f, 0.0f};
    #pragma unroll
    for (int c = 0; c < 4; ++c) { oA[c] = zero4; oB[c] = zero4; }
    float mA = MASK2, lA = 0.0f, mB = MASK2, lB = 0.0f;

    // ---- staging addressing: thread owns kv rows 4*sr..4*sr+3, d block d0..d0+3 ----
    const int sr = tid >> 4;      // 0..15
    const int cb = tid & 15;
    const int d0 = cb * 4;

    f32x4_t kreg[4], vreg[4];     // tile data in flight during compute

    auto issue = [&](int kt0) {
        const float* kr = kp + (size_t)(kt0 + 4 * sr) * HD + d0;
        const float* vr = vp + (size_t)(kt0 + 4 * sr) * HD + d0;
        #pragma unroll
        for (int i = 0; i < 4; ++i) {
            kreg[i] = *(const f32x4_t*)(kr + i * HD);
            vreg[i] = *(const f32x4_t*)(vr + i * HD);
        }
    };

    auto stage = [&]() {
        #pragma unroll
        for (int i = 0; i < 4; ++i) {
            const int r0 = 4 * sr + i;
            short4_t kw;
            #pragma unroll
            for (int j = 0; j < 4; ++j) kw[j] = __builtin_bit_cast(short, (__bf16)kreg[i][j]);
            *(short4_t*)&k_lds[swz(r0, cb >> 1) + (cb & 1) * 4] = kw;
        }
        #pragma unroll
        for (int j = 0; j < 4; ++j) {
            short4_t vw;
            #pragma unroll
            for (int i = 0; i < 4; ++i) vw[i] = __builtin_bit_cast(short, (__bf16)vreg[i][j]);
            *(short4_t*)&vt_lds[swz(d0 + j, sr >> 1) + (sr & 1) * 4] = vw;
        }
    };

    const int qloc = wave * 16 + l16;   // diag-tile local q row (same for A and B sets)

    // online softmax on 16 lane-local scores + P store (rows prow_)
    auto softmax_pstore = [&](const f32x4_t (&s)[4], float& m, float& l,
                              f32x4_t (&o)[4], bool diag, int prow_) {
        float sv[4][4];
        float vmax = MASK2;
        #pragma unroll
        for (int c = 0; c < 4; ++c) {
            #pragma unroll
            for (int r = 0; r < 4; ++r) {
                float x = s[c][r];
                if (diag && (c * 16 + quad * 4 + r > qloc)) x = MASK2;
                sv[c][r] = x;
                vmax = fmaxf(vmax, x);
            }
        }
        vmax = fmaxf(vmax, __shfl_xor(vmax, 16));
        vmax = fmaxf(vmax, __shfl_xor(vmax, 32));
        if (__any((int)(vmax > m))) {
            float mn = fmaxf(m, vmax);
            float a  = __builtin_amdgcn_exp2f(m - mn);   // arg <= 0
            m = mn;
            l *= a;
            float ar[4];
            #pragma unroll
            for (int r = 0; r < 4; ++r)
                ar[r] = __shfl(a, (lane & 48) | (quad * 4 + r));
            #pragma unroll
            for (int c = 0; c < 4; ++c)
                #pragma unroll
                for (int r = 0; r < 4; ++r)
                    o[c][r] *= ar[r];
        }
        float rs = 0.0f;
        #pragma unroll
        for (int c = 0; c < 4; ++c) {
            short4_t pw;
            #pragma unroll
            for (int r = 0; r < 4; ++r) {
                float p = __builtin_amdgcn_exp2f(sv[c][r] - m);  // arg <= 0
                rs += p;
                pw[r] = __builtin_bit_cast(short, (__bf16)p);
            }
            *(short4_t*)&p_lds[swz(prow_, 2 * c + (quad >> 1)) + (quad & 1) * 4] = pw;
        }
        rs += __shfl_xor(rs, 16);
        rs += __shfl_xor(rs, 32);
        l += rs;
    };

    issue(0);   // prologue: tile 0 in flight

    for (int t = 0; t < ntB; ++t) {
        const int kt0 = t * BKV;
        __syncthreads();            // A: prior iteration's LDS readers done
        stage();                    // regs (tile t) -> LDS, bf16 convert
        __syncthreads();            // B: staged tile visible
        if (t + 1 < ntB) issue(kt0 + BKV);   // tile t+1 in flight during compute

        const bool doA   = (t < ntA);       // A's causal range is the prefix
        const bool diagA = (t == ntA - 1);
        const bool diagB = (t == ntB - 1);

        // ---- S^T = K Q^T : D[m=kv][n=q]; K-frag reads shared between A and B ----
        f32x4_t sA[4], sB[4];
        #pragma unroll
        for (int c = 0; c < 4; ++c) { sA[c] = zero4; sB[c] = zero4; }
        __builtin_amdgcn_s_setprio(1);
        #pragma unroll
        for (int c = 0; c < 4; ++c) {
            const int kvrow = c * 16 + l16;
            bf16x8_t kf0 = __builtin_bit_cast(bf16x8_t, *(const short8_t*)&k_lds[swz(kvrow, quad)]);
            bf16x8_t kf1 = __builtin_bit_cast(bf16x8_t, *(const short8_t*)&k_lds[swz(kvrow, quad + 4)]);
            if (doA) {
                sA[c] = __builtin_amdgcn_mfma_f32_16x16x32_bf16(kf0, qfA0, sA[c], 0, 0, 0);
                sA[c] = __builtin_amdgcn_mfma_f32_16x16x32_bf16(kf1, qfA1, sA[c], 0, 0, 0);
            }
            sB[c] = __builtin_amdgcn_mfma_f32_16x16x32_bf16(kf0, qfB0, sB[c], 0, 0, 0);
            sB[c] = __builtin_amdgcn_mfma_f32_16x16x32_bf16(kf1, qfB1, sB[c], 0, 0, 0);
        }
        __builtin_amdgcn_s_setprio(0);

        // ---- online softmax + P stores (A rows 0-63, B rows 64-127) ----
        const int prowA = wave * 16 + l16;
        if (doA) softmax_pstore(sA, mA, lA, oA, diagA, prowA);
        softmax_pstore(sB, mB, lB, oB, diagB, 64 + prowA);

        // NO barrier: P tiles written and read within the same wave (lgkmcnt orders)

        // ---- O += P V : V^T reads shared between A and B ----
        bf16x8_t pfA0, pfA1;
        if (doA) {
            pfA0 = __builtin_bit_cast(bf16x8_t, *(const short8_t*)&p_lds[swz(prowA, quad)]);
            pfA1 = __builtin_bit_cast(bf16x8_t, *(const short8_t*)&p_lds[swz(prowA, quad + 4)]);
        }
        bf16x8_t pfB0 = __builtin_bit_cast(bf16x8_t, *(const short8_t*)&p_lds[swz(64 + prowA, quad)]);
        bf16x8_t pfB1 = __builtin_bit_cast(bf16x8_t, *(const short8_t*)&p_lds[swz(64 + prowA, quad + 4)]);
        __builtin_amdgcn_s_setprio(1);
        #pragma unroll
        for (int c = 0; c < 4; ++c) {
            const int d = c * 16 + l16;
            bf16x8_t b0 = __builtin_bit_cast(bf16x8_t, *(const short8_t*)&vt_lds[swz(d, quad)]);
            bf16x8_t b1 = __builtin_bit_cast(bf16x8_t, *(const short8_t*)&vt_lds[swz(d, quad + 4)]);
            if (doA) {
                oA[c] = __builtin_amdgcn_mfma_f32_16x16x32_bf16(pfA0, b0, oA[c], 0, 0, 0);
                oA[c] = __builtin_amdgcn_mfma_f32_16x16x32_bf16(pfA1, b1, oA[c], 0, 0, 0);
            }
            oB[c] = __builtin_amdgcn_mfma_f32_16x16x32_bf16(pfB0, b0, oB[c], 0, 0, 0);
            oB[c] = __builtin_amdgcn_mfma_f32_16x16x32_bf16(pfB1, b1, oB[c], 0, 0, 0);
        }
        __builtin_amdgcn_s_setprio(0);
    }

    // ---- epilogue: O / l, fp32 store to out[b][q][h*64 + d] ----
    const int b = bh >> 4;
    const int h = bh & 15;
    auto store_o = [&](const f32x4_t (&o)[4], float l, int row_base) {
        #pragma unroll
        for (int r = 0; r < 4; ++r) {
            const float lr = __shfl(l, (lane & 48) | (quad * 4 + r));
            const float inv_l = 1.0f / fmaxf(lr, 1e-30f);
            const int row = row_base + quad * 4 + r;
            float* op = outg + ((size_t)b * SEQ + row) * (NH * HD) + h * HD;
            #pragma unroll
            for (int c = 0; c < 4; ++c) {
                float val = o[c][r] * inv_l;
                unsigned bits = __builtin_bit_cast(unsigned, val);
                if ((bits & 0x7F800000u) == 0x7F800000u) val = 0.0f;  // scrub inf/NaN
                op[c * 16 + l16] = val;
            }
        }
    };
    store_o(oA, lA, q0A + wave * 16);
    store_o(oB, lB, q0B + wave * 16);
}

extern "C" void kernel_launch(void* const* d_in, const int* in_sizes, int n_in,
                              void* d_out, int out_size, void* d_ws, size_t ws_size,
                              hipStream_t stream) {
    const float* q = (const float*)d_in[0];
    const float* k = (const float*)d_in[1];
    const float* v = (const float*)d_in[2];
    float* out = (float*)d_out;
    dim3 grid(NB * NH, NQT / 2);   // x = bh, y = pair index (q-tiles i and 31-i)
    fa_fwd<<<grid, 256, 0, stream>>>(q, k, v, out);
}

// Round 5
// 199.713 us; speedup vs baseline: 1.3002x; 1.3002x over previous
//
#include <hip/hip_runtime.h>
#include <hip/hip_bf16.h>

typedef __bf16 bf16x8_t __attribute__((ext_vector_type(8)));
typedef float  f32x4_t  __attribute__((ext_vector_type(4)));
typedef short  short8_t __attribute__((ext_vector_type(8)));
typedef short  short4_t __attribute__((ext_vector_type(4)));

#define NB   4
#define NH   16
#define SEQ  2048
#define HD   64
#define BKV  64
#define LSTR 72    // LDS row stride in bf16 elems: 144B rows, 16B-aligned blocks

// masked score in base-2 domain: WHERE_CONST * log2(e)
#define MASK2 (-14426.950408889634f)
// softmax scale folded into Q: (1/sqrt(64)) * log2(e)
#define QSCL  (0.18033688011112042f)

// uniform swizzled LDS address (shorts): row*72 + ((blk ^ (row>>3)) & 7) * 8
__device__ __forceinline__ int swz(int rowi, int blk) {
    return rowi * LSTR + (((blk) ^ (rowi >> 3)) & 7) * 8;
}

__global__ void __launch_bounds__(256)
fa_fwd(const float* __restrict__ qg,
       const float* __restrict__ kg,
       const float* __restrict__ vg,
       float* __restrict__ outg) {
    __shared__ alignas(16) short k_lds[BKV * LSTR];    // K tile bf16 [kv][d], block-swizzled
    __shared__ alignas(16) short vt_lds[HD * LSTR];    // V^T tile bf16 [d][kv], block-swizzled
    __shared__ alignas(16) short p_lds[128 * LSTR];    // P bf16: A rows 0-63, B rows 64-127

    const int tid  = threadIdx.x;
    const int wave = tid >> 6;
    const int lane = tid & 63;
    const int l16  = lane & 15;
    const int quad = lane >> 4;

    // grid: x = bh (64), y = bin z (8). Bin z = pairs {P_(15-z), P_z} where
    // pair P_a = q-tiles (2a, 2a+1) costing 2a+2 shell-iterations.
    // Every bin costs exactly (32-2z)+(2z+2) = 34 shells -> perfectly uniform blocks.
    const int bh = blockIdx.x;
    const int z  = blockIdx.y;

    const size_t base = (size_t)bh * SEQ * HD;
    const float* qp = qg + base;
    const float* kp = kg + base;
    const float* vp = vg + base;

    // ---- staging addressing: thread owns kv rows 4*sr..4*sr+3, d block d0..d0+3 ----
    const int sr = tid >> 4;      // 0..15
    const int cb = tid & 15;
    const int d0 = cb * 4;

    f32x4_t kreg[4], vreg[4];     // tile data in flight during compute

    auto issue = [&](int kt0) {
        const float* kr = kp + (size_t)(kt0 + 4 * sr) * HD + d0;
        const float* vr = vp + (size_t)(kt0 + 4 * sr) * HD + d0;
        #pragma unroll
        for (int i = 0; i < 4; ++i) {
            kreg[i] = *(const f32x4_t*)(kr + i * HD);
            vreg[i] = *(const f32x4_t*)(vr + i * HD);
        }
    };

    auto stage = [&]() {
        #pragma unroll
        for (int i = 0; i < 4; ++i) {
            const int r0 = 4 * sr + i;
            short4_t kw;
            #pragma unroll
            for (int j = 0; j < 4; ++j) kw[j] = __builtin_bit_cast(short, (__bf16)kreg[i][j]);
            *(short4_t*)&k_lds[swz(r0, cb >> 1) + (cb & 1) * 4] = kw;
        }
        #pragma unroll
        for (int j = 0; j < 4; ++j) {
            short4_t vw;
            #pragma unroll
            for (int i = 0; i < 4; ++i) vw[i] = __builtin_bit_cast(short, (__bf16)vreg[i][j]);
            *(short4_t*)&vt_lds[swz(d0 + j, sr >> 1) + (sr & 1) * 4] = vw;
        }
    };

    const int qloc = wave * 16 + l16;   // diag-tile local q row (same for A and B sets)

    // online softmax on 16 lane-local scores + P store (rows prow_)
    auto softmax_pstore = [&](const f32x4_t (&s)[4], float& m, float& l,
                              f32x4_t (&o)[4], bool diag, int prow_) {
        float sv[4][4];
        float vmax = MASK2;
        #pragma unroll
        for (int c = 0; c < 4; ++c) {
            #pragma unroll
            for (int r = 0; r < 4; ++r) {
                float x = s[c][r];
                if (diag && (c * 16 + quad * 4 + r > qloc)) x = MASK2;
                sv[c][r] = x;
                vmax = fmaxf(vmax, x);
            }
        }
        vmax = fmaxf(vmax, __shfl_xor(vmax, 16));
        vmax = fmaxf(vmax, __shfl_xor(vmax, 32));
        if (__any((int)(vmax > m))) {
            float mn = fmaxf(m, vmax);
            float a  = __builtin_amdgcn_exp2f(m - mn);   // arg <= 0
            m = mn;
            l *= a;
            float ar[4];
            #pragma unroll
            for (int r = 0; r < 4; ++r)
                ar[r] = __shfl(a, (lane & 48) | (quad * 4 + r));
            #pragma unroll
            for (int c = 0; c < 4; ++c)
                #pragma unroll
                for (int r = 0; r < 4; ++r)
                    o[c][r] *= ar[r];
        }
        float rs = 0.0f;
        #pragma unroll
        for (int c = 0; c < 4; ++c) {
            short4_t pw;
            #pragma unroll
            for (int r = 0; r < 4; ++r) {
                float p = __builtin_amdgcn_exp2f(sv[c][r] - m);  // arg <= 0
                rs += p;
                pw[r] = __builtin_bit_cast(short, (__bf16)p);
            }
            *(short4_t*)&p_lds[swz(prow_, 2 * c + (quad >> 1)) + (quad & 1) * 4] = pw;
        }
        rs += __shfl_xor(rs, 16);
        rs += __shfl_xor(rs, 32);
        l += rs;
    };

    const int b = bh >> 4;
    const int h = bh & 15;
    auto store_o = [&](const f32x4_t (&o)[4], float l, int row_base) {
        #pragma unroll
        for (int r = 0; r < 4; ++r) {
            const float lr = __shfl(l, (lane & 48) | (quad * 4 + r));
            const float inv_l = 1.0f / fmaxf(lr, 1e-30f);
            const int row = row_base + quad * 4 + r;
            float* op = outg + ((size_t)b * SEQ + row) * (NH * HD) + h * HD;
            #pragma unroll
            for (int c = 0; c < 4; ++c) {
                float val = o[c][r] * inv_l;
                unsigned bits = __builtin_bit_cast(unsigned, val);
                if ((bits & 0x7F800000u) == 0x7F800000u) val = 0.0f;  // scrub inf/NaN
                op[c * 16 + l16] = val;
            }
        }
    };

    const f32x4_t zero4 = {0.0f, 0.0f, 0.0f, 0.0f};

    #pragma unroll 1
    for (int pp = 0; pp < 2; ++pp) {
        const int a   = (pp == 0) ? (15 - z) : z;   // pair index: heavy pair first
        const int q0A = a * 128;                    // q-tile 2a
        const int q0B = q0A + 64;                   // q-tile 2a+1
        const int ntA = 2 * a + 1;                  // KV tiles set A needs
        const int ntB = 2 * a + 2;                  // KV tiles set B needs

        // ---- Q fragments (B-operand in swapped QK^T): q=l16-row, d=quad*8+j ----
        bf16x8_t qfA0, qfA1, qfB0, qfB1;
        {
            const float* qrA = qp + (size_t)(q0A + wave * 16 + l16) * HD;
            const float* qrB = qp + (size_t)(q0B + wave * 16 + l16) * HD;
            f32x4_t a0 = *(const f32x4_t*)(qrA + quad * 8);
            f32x4_t a1 = *(const f32x4_t*)(qrA + quad * 8 + 4);
            f32x4_t a2 = *(const f32x4_t*)(qrA + 32 + quad * 8);
            f32x4_t a3 = *(const f32x4_t*)(qrA + 32 + quad * 8 + 4);
            f32x4_t b0 = *(const f32x4_t*)(qrB + quad * 8);
            f32x4_t b1 = *(const f32x4_t*)(qrB + quad * 8 + 4);
            f32x4_t b2 = *(const f32x4_t*)(qrB + 32 + quad * 8);
            f32x4_t b3 = *(const f32x4_t*)(qrB + 32 + quad * 8 + 4);
            #pragma unroll
            for (int j = 0; j < 4; ++j) {
                qfA0[j]     = (__bf16)(a0[j] * QSCL);
                qfA0[4 + j] = (__bf16)(a1[j] * QSCL);
                qfA1[j]     = (__bf16)(a2[j] * QSCL);
                qfA1[4 + j] = (__bf16)(a3[j] * QSCL);
                qfB0[j]     = (__bf16)(b0[j] * QSCL);
                qfB0[4 + j] = (__bf16)(b1[j] * QSCL);
                qfB1[j]     = (__bf16)(b2[j] * QSCL);
                qfB1[4 + j] = (__bf16)(b3[j] * QSCL);
            }
        }

        f32x4_t oA[4], oB[4];
        #pragma unroll
        for (int c = 0; c < 4; ++c) { oA[c] = zero4; oB[c] = zero4; }
        float mA = MASK2, lA = 0.0f, mB = MASK2, lB = 0.0f;

        issue(0);   // prologue: tile 0 in flight

        #pragma unroll 1
        for (int t = 0; t < ntB; ++t) {
            const int kt0 = t * BKV;
            __syncthreads();            // prior LDS readers done (also covers pair switch)
            stage();                    // regs (tile t) -> LDS, bf16 convert
            __syncthreads();            // staged tile visible
            if (t + 1 < ntB) issue(kt0 + BKV);   // tile t+1 in flight during compute

            const bool doA   = (t < ntA);       // A's causal range is the prefix
            const bool diagA = (t == ntA - 1);
            const bool diagB = (t == ntB - 1);

            // ---- S^T = K Q^T : D[m=kv][n=q]; K-frag reads shared between A and B ----
            f32x4_t sA[4], sB[4];
            #pragma unroll
            for (int c = 0; c < 4; ++c) { sA[c] = zero4; sB[c] = zero4; }
            __builtin_amdgcn_s_setprio(1);
            #pragma unroll
            for (int c = 0; c < 4; ++c) {
                const int kvrow = c * 16 + l16;
                bf16x8_t kf0 = __builtin_bit_cast(bf16x8_t, *(const short8_t*)&k_lds[swz(kvrow, quad)]);
                bf16x8_t kf1 = __builtin_bit_cast(bf16x8_t, *(const short8_t*)&k_lds[swz(kvrow, quad + 4)]);
                if (doA) {
                    sA[c] = __builtin_amdgcn_mfma_f32_16x16x32_bf16(kf0, qfA0, sA[c], 0, 0, 0);
                    sA[c] = __builtin_amdgcn_mfma_f32_16x16x32_bf16(kf1, qfA1, sA[c], 0, 0, 0);
                }
                sB[c] = __builtin_amdgcn_mfma_f32_16x16x32_bf16(kf0, qfB0, sB[c], 0, 0, 0);
                sB[c] = __builtin_amdgcn_mfma_f32_16x16x32_bf16(kf1, qfB1, sB[c], 0, 0, 0);
            }
            __builtin_amdgcn_s_setprio(0);

            // ---- online softmax + P stores (A rows 0-63, B rows 64-127) ----
            const int prowA = wave * 16 + l16;
            if (doA) softmax_pstore(sA, mA, lA, oA, diagA, prowA);
            softmax_pstore(sB, mB, lB, oB, diagB, 64 + prowA);

            // NO barrier: P tiles written and read within the same wave (lgkmcnt orders)

            // ---- O += P V : V^T reads shared between A and B ----
            bf16x8_t pfA0, pfA1;
            if (doA) {
                pfA0 = __builtin_bit_cast(bf16x8_t, *(const short8_t*)&p_lds[swz(prowA, quad)]);
                pfA1 = __builtin_bit_cast(bf16x8_t, *(const short8_t*)&p_lds[swz(prowA, quad + 4)]);
            }
            bf16x8_t pfB0 = __builtin_bit_cast(bf16x8_t, *(const short8_t*)&p_lds[swz(64 + prowA, quad)]);
            bf16x8_t pfB1 = __builtin_bit_cast(bf16x8_t, *(const short8_t*)&p_lds[swz(64 + prowA, quad + 4)]);
            __builtin_amdgcn_s_setprio(1);
            #pragma unroll
            for (int c = 0; c < 4; ++c) {
                const int d = c * 16 + l16;
                bf16x8_t b0 = __builtin_bit_cast(bf16x8_t, *(const short8_t*)&vt_lds[swz(d, quad)]);
                bf16x8_t b1 = __builtin_bit_cast(bf16x8_t, *(const short8_t*)&vt_lds[swz(d, quad + 4)]);
                if (doA) {
                    oA[c] = __builtin_amdgcn_mfma_f32_16x16x32_bf16(pfA0, b0, oA[c], 0, 0, 0);
                    oA[c] = __builtin_amdgcn_mfma_f32_16x16x32_bf16(pfA1, b1, oA[c], 0, 0, 0);
                }
                oB[c] = __builtin_amdgcn_mfma_f32_16x16x32_bf16(pfB0, b0, oB[c], 0, 0, 0);
                oB[c] = __builtin_amdgcn_mfma_f32_16x16x32_bf16(pfB1, b1, oB[c], 0, 0, 0);
            }
            __builtin_amdgcn_s_setprio(0);
        }

        // ---- epilogue for this pair: O / l, fp32 store to out[b][q][h*64 + d] ----
        store_o(oA, lA, q0A + wave * 16);
        store_o(oB, lB, q0B + wave * 16);
    }
}

extern "C" void kernel_launch(void* const* d_in, const int* in_sizes, int n_in,
                              void* d_out, int out_size, void* d_ws, size_t ws_size,
                              hipStream_t stream) {
    const float* q = (const float*)d_in[0];
    const float* k = (const float*)d_in[1];
    const float* v = (const float*)d_in[2];
    float* out = (float*)d_out;
    dim3 grid(NB * NH, 8);   // x = bh, y = bin z; every block = exactly 34 shell-iterations
    fa_fwd<<<grid, 256, 0, stream>>>(q, k, v, out);
}